// Round 8
// baseline (100.027 us; speedup 1.0000x reference)
//
#include <hip/hip_runtime.h>

// B=32, C=8, L=2048, K=512, S=64, W=1985
// out[b,0,q] = max(0, max_w sum_c dot(xw_n[b,c,w,:], sn_n[c,q,:]) / 8)
//
// v9: occupancy doubling. v5/v7/v8 proved the ~45us wall is invariant to the
// feed schedule (drain / counted-vmcnt / barrier-free all ~30% MfmaUtil) --
// the limiter is 2 waves/SIMD unable to hide each wave's per-c latency chain.
// v9: 512-thread blocks (8 waves), wave tile 32 windows x 64 q (acc = 32
// regs, ~115 total, fits the 128-reg cap of __launch_bounds__(512,4)).
// 2 blocks/CU -> 16 waves/CU = 4 waves/SIMD, same persistent-LDS B-panel
// (64 KB, staged once, barrier-free c-loop), same MFMA:feed ratio per wave.

#define B_ 32
#define C_ 8
#define L_ 2048
#define K_ 512
#define S_ 64
#define W_ 1985
#define XS_ 2176                      // padded f16 row stride (L_ + 128)

typedef _Float16 f16x8  __attribute__((ext_vector_type(8)));
typedef _Float16 f16x8u __attribute__((ext_vector_type(8), aligned(4)));
typedef float    f32x16 __attribute__((ext_vector_type(16)));

// ---- prologue (unchanged, harness-verified) ----
__global__ __launch_bounds__(256)
void prep_k(const float* __restrict__ x, const float* __restrict__ sh,
            _Float16* __restrict__ Bp, float* __restrict__ invn,
            _Float16* __restrict__ xh0, _Float16* __restrict__ xh1,
            float* __restrict__ out) {
    __shared__ float xr[L_];
    const int tid = threadIdx.x;
    const int blk = blockIdx.x;

    if (blk < 128) {
        const int sb   = blk * 4 + (tid >> 6);   // 0..511 = c(8) x kq(4) x nt(16)
        const int c    = sb >> 6;
        const int kq   = (sb >> 4) & 3;
        const int nt   = sb & 15;
        const int lane = tid & 63;
        const int half = lane >> 5;
        const int q    = nt * 32 + (lane & 31);

        const float4* sp = (const float4*)(sh + (size_t)(c * K_ + q) * S_);
        float ss = 0.f;
        #pragma unroll
        for (int i = 0; i < 8; ++i) {
            float4 v = sp[half * 8 + i];
            ss += v.x * v.x + v.y * v.y + v.z * v.z + v.w * v.w;
        }
        ss += __shfl_xor(ss, 32);
        float inv = 1.f / fmaxf(sqrtf(ss), 1e-8f);

        float4 u0 = sp[kq * 4 + half * 2];
        float4 u1 = sp[kq * 4 + half * 2 + 1];
        f16x8 o;
        o[0] = (_Float16)(u0.x * inv); o[1] = (_Float16)(u0.y * inv);
        o[2] = (_Float16)(u0.z * inv); o[3] = (_Float16)(u0.w * inv);
        o[4] = (_Float16)(u1.x * inv); o[5] = (_Float16)(u1.y * inv);
        o[6] = (_Float16)(u1.z * inv); o[7] = (_Float16)(u1.w * inv);
        ((f16x8*)Bp)[((c * 4 + kq) * 16 + nt) * 64 + lane] = o;
    } else {
        const int r = blk - 128;                 // 0..255 = b*8+c
        const float* xp = x + (size_t)r * L_;
        for (int i = tid; i < L_ / 4; i += 256)
            ((float4*)xr)[i] = ((const float4*)xp)[i];
        __syncthreads();

        float* ivp = invn + (size_t)r * L_;
        const int w0 = tid * 8;
        float ss = 0.f;
        if (w0 < W_) {
            #pragma unroll
            for (int j = 0; j < S_; ++j) { float v = xr[w0 + j]; ss += v * v; }
        }
        #pragma unroll
        for (int u = 0; u < 8; ++u) {
            int w = w0 + u;
            float o = 0.f;
            if (u > 0 && w < W_)
                ss += xr[w + 63] * xr[w + 63] - xr[w - 1] * xr[w - 1];
            if (w < W_) o = 0.125f / fmaxf(sqrtf(ss), 1e-8f);
            if (w < L_) ivp[w] = o;
        }

        _Float16* p0 = xh0 + (size_t)r * XS_;
        _Float16* p1 = xh1 + (size_t)r * XS_;
        for (int i = tid; i < XS_ / 8; i += 256) {
            f16x8 o0, o1;
            #pragma unroll
            for (int j = 0; j < 8; ++j) {
                int e = i * 8 + j;
                o0[j] = (_Float16)((e     < L_) ? xr[e]     : 0.f);
                o1[j] = (_Float16)((e + 1 < L_) ? xr[e + 1] : 0.f);
            }
            ((f16x8*)p0)[i] = o0;
            ((f16x8*)p1)[i] = o1;
        }
        if (r < 64) out[r * 256 + tid] = 0.f;    // zero output
    }
}

// global -> LDS direct copy, 16B per lane (dest = uniform base + lane*16)
__device__ __forceinline__ void glds16(const void* g, void* l) {
    __builtin_amdgcn_global_load_lds(
        (const __attribute__((address_space(1))) unsigned int*)g,
        (__attribute__((address_space(3))) unsigned int*)l, 16, 0, 0);
}

// A fragments (4 x f16x8 = 16 VGPR) + inv-norm for channel c (5 VMEM)
__device__ __forceinline__ void loadA(
    int c, const _Float16* __restrict__ xbase, const float* __restrict__ ivbase,
    int m0, f16x8 (&ar)[4], float &iv)
{
    iv = ivbase[(size_t)c * L_ + m0];            // 0 for invalid windows
    const _Float16* xp = xbase + (size_t)c * XS_;
    #pragma unroll
    for (int ks = 0; ks < 4; ++ks)
        ar[ks] = *(const f16x8u*)(xp + ks * 16);
}

// 8 ds_read_b128 (persistent B panel) + scale A + 8 MFMAs
__device__ __forceinline__ void compC(
    int c, const f16x8* __restrict__ bsl, int lane,
    const f16x8 (&ar)[4], float iv, f32x16 (&acc)[2])
{
    f16x8 bf[8];
    #pragma unroll
    for (int ks = 0; ks < 4; ++ks)
        #pragma unroll
        for (int nt = 0; nt < 2; ++nt)
            bf[ks * 2 + nt] = bsl[(c * 8 + ks * 2 + nt) * 64 + lane];

    const _Float16 h = (_Float16)iv;
    f16x8 is;
    #pragma unroll
    for (int j = 0; j < 8; ++j) is[j] = h;

    __builtin_amdgcn_s_setprio(1);
    #pragma unroll
    for (int ks = 0; ks < 4; ++ks) {
        f16x8 a = ar[ks] * is;                   // v_pk_mul_f16 x4
        acc[0] = __builtin_amdgcn_mfma_f32_32x32x16_f16(
            a, bf[ks * 2 + 0], acc[0], 0, 0, 0);
        acc[1] = __builtin_amdgcn_mfma_f32_32x32x16_f16(
            a, bf[ks * 2 + 1], acc[1], 0, 0, 0);
    }
    __builtin_amdgcn_s_setprio(0);
}

// ---- main: 8-wave blocks, persistent-LDS B, barrier-free c-loop ----
// grid (8 wt, 8 ng, 32 b) = 2048 blocks x 512 thr. Block: 256 windows x
// 64 q. Wave: 32 windows x 64 q (2x32); acc = 2 x f32x16 = 32 regs.
// Stage the block's B-panel (64 x 1KB units) once (8 glds16/wave), one
// __syncthreads, then c-loop with A reg-prefetch, no barriers. Epilogue:
// per-wave row-max, LDS cross-wave max, 64 atomics/block.
__global__ __launch_bounds__(512, 4)
void mcs_k(const _Float16* __restrict__ xh0, const _Float16* __restrict__ xh1,
           const _Float16* __restrict__ Bp, const float* __restrict__ invn,
           float* __restrict__ out) {
    const int wt  = blockIdx.x;           // 0..7  256-window tile
    const int ng  = blockIdx.y;           // 0..7  64-q panel
    const int b   = blockIdx.z;
    const int tid = threadIdx.x;
    const int lane = tid & 63;
    const int wv   = tid >> 6;            // wave 0..7 = window subgroup

    const int l31 = lane & 31;
    const int lh  = lane >> 5;
    const int Wb  = wt * 256 + wv * 32;   // wave's window base (max 2016)
    const int m0  = Wb + l31;             // lane's window row (max 2047)

    __shared__ f16x8 Bs[64][64];          // 64 KB: unit e = c*8+ks*2+nt
    __shared__ float red[8][2][32];       // cross-wave max scratch

    // ---- stage B-panel once: wave wv stages channel c=wv (units e=wv*8+u)
    {
        const f16x8* bp = (const f16x8*)Bp;
        #pragma unroll
        for (int u = 0; u < 8; ++u) {
            const int e   = wv * 8 + u;
            const int c   = e >> 3;                   // = wv
            const int sub = e & 7;                    // ks*2 + nt
            const int src = ((c * 4 + (sub >> 1)) * 16 + ng * 2 + (sub & 1)) * 64;
            glds16(bp + src + lane, &Bs[e][0]);
        }
    }

    // parity-selected x base keeps every f16x8 load 4B-aligned
    const _Float16* xb = (l31 & 1) ? (xh1 - 1) : xh0;
    const _Float16* xbase = xb + (size_t)b * C_ * XS_ + Wb + l31 + lh * 8;
    const float*   ivbase = invn + (size_t)b * C_ * L_;

    f32x16 acc[2];
    #pragma unroll
    for (int nt = 0; nt < 2; ++nt)
        #pragma unroll
        for (int r = 0; r < 16; ++r) acc[nt][r] = 0.f;

    f16x8 aA[4], aB[4];
    float ivA, ivB;

    loadA(0, xbase, ivbase, m0, aA, ivA);   // overlaps the staging
    __syncthreads();                        // B-panel ready (vmcnt drained)

    #pragma unroll 1
    for (int cp = 0; cp < 4; ++cp) {
        const int c0 = cp * 2;
        loadA(c0 + 1, xbase, ivbase, m0, aB, ivB);
        compC(c0, &Bs[0][0], lane, aA, ivA, acc);
        if (cp < 3)
            loadA(c0 + 2, xbase, ivbase, m0, aA, ivA);
        compC(c0 + 1, &Bs[0][0], lane, aB, ivB, acc);
    }

    // epilogue: relu + max over this wave's 32 windows (rows), then
    // cross-wave max via LDS, one atomicMax per (nt,col) per block.
    float m[2];
    #pragma unroll
    for (int nt = 0; nt < 2; ++nt) {
        float v = 0.f;
        #pragma unroll
        for (int r = 0; r < 16; ++r) v = fmaxf(v, acc[nt][r]);
        v = fmaxf(v, __shfl_xor(v, 32));    // fold lane-half (same column)
        m[nt] = v;
    }
    if (lane < 32) {
        red[wv][0][l31] = m[0];
        red[wv][1][l31] = m[1];
    }
    __syncthreads();
    if (tid < 64) {
        const int nt  = tid >> 5;
        const int col = tid & 31;
        float v = red[0][nt][col];
        #pragma unroll
        for (int w2 = 1; w2 < 8; ++w2) v = fmaxf(v, red[w2][nt][col]);
        atomicMax((unsigned int*)(out + (size_t)b * K_ + ng * 64 + nt * 32 + col),
                  __float_as_uint(v));      // values >= 0, uint-max valid
    }
}

extern "C" void kernel_launch(void* const* d_in, const int* in_sizes, int n_in,
                              void* d_out, int out_size, void* d_ws, size_t ws_size,
                              hipStream_t stream) {
    const float* x  = (const float*)d_in[0];   // (32, 8, 2048) fp32
    const float* sh = (const float*)d_in[1];   // (8, 512, 64) fp32
    float* out = (float*)d_out;                // (32, 1, 512) fp32

    // workspace: Bp 512KB | invn 2MB | xh0 ~1.06MB | xh1 ~1.06MB
    _Float16* Bp   = (_Float16*)d_ws;
    float*    invn = (float*)((char*)d_ws + (512 << 10));
    _Float16* xh0  = (_Float16*)((char*)d_ws + (512 << 10) + (2 << 20));
    _Float16* xh1  = xh0 + (size_t)B_ * C_ * XS_;

    prep_k<<<dim3(384), dim3(256), 0, stream>>>(x, sh, Bp, invn, xh0, xh1, out);
    mcs_k<<<dim3(8, 8, B_), dim3(512), 0, stream>>>(xh0, xh1, Bp, invn, out);
}

// Round 9
// 95.103 us; speedup vs baseline: 1.0518x; 1.0518x over previous
//
#include <hip/hip_runtime.h>

// B=32, C=8, L=2048, K=512, S=64, W=1985
// out[b,0,q] = max(0, max_w sum_c dot(xw_n[b,c,w,:], sn_n[c,q,:]) / 8)
//
// v10: A-feed off the TA path. v8 vs v9 showed a wall (~46us, MfmaUtil 30%)
// invariant to schedule AND occupancy -> shared-resource bound. The one
// component never varied: the A sliding-window gather (overlapping 16B/lane
// global loads, ~2560/CU, ~40cyc each ~= the wall). v10 stages the block's
// x-slab into LDS once (13KB, 2 parity copies) and builds A-frags from LDS
// dword reads (4B-aligned via parity copies; <=2-way banks = free). Hankel
// reuse: a(mt,ks)=g(2mt+ks) -> 6 A-frags/c. Main-loop TA ~600 instr/CU.
// Geometry = v8: 4 waves x (64w x 64q), persistent 64KB B-panel, barrier-free.

#define B_ 32
#define C_ 8
#define L_ 2048
#define K_ 512
#define S_ 64
#define W_ 1985
#define XS_ 2176                      // padded f16 row stride (L_ + 128)
#define XSLAB_ 416                    // f16 elems per (c,parity) LDS region
#define XSLDW_ 208                    // dwords per region

typedef _Float16 f16x8  __attribute__((ext_vector_type(8)));
typedef float    f32x16 __attribute__((ext_vector_type(16)));

// ---- prologue (same as harness-verified v3..v9) ----
__global__ __launch_bounds__(256)
void prep_k(const float* __restrict__ x, const float* __restrict__ sh,
            _Float16* __restrict__ Bp, float* __restrict__ invn,
            _Float16* __restrict__ xh0, _Float16* __restrict__ xh1,
            float* __restrict__ out) {
    __shared__ float xr[L_];
    const int tid = threadIdx.x;
    const int blk = blockIdx.x;

    if (blk < 128) {
        const int sb   = blk * 4 + (tid >> 6);   // 0..511 = c(8) x kq(4) x nt(16)
        const int c    = sb >> 6;
        const int kq   = (sb >> 4) & 3;
        const int nt   = sb & 15;
        const int lane = tid & 63;
        const int half = lane >> 5;
        const int q    = nt * 32 + (lane & 31);

        const float4* sp = (const float4*)(sh + (size_t)(c * K_ + q) * S_);
        float ss = 0.f;
        #pragma unroll
        for (int i = 0; i < 8; ++i) {
            float4 v = sp[half * 8 + i];
            ss += v.x * v.x + v.y * v.y + v.z * v.z + v.w * v.w;
        }
        ss += __shfl_xor(ss, 32);
        float inv = 1.f / fmaxf(sqrtf(ss), 1e-8f);

        float4 u0 = sp[kq * 4 + half * 2];
        float4 u1 = sp[kq * 4 + half * 2 + 1];
        f16x8 o;
        o[0] = (_Float16)(u0.x * inv); o[1] = (_Float16)(u0.y * inv);
        o[2] = (_Float16)(u0.z * inv); o[3] = (_Float16)(u0.w * inv);
        o[4] = (_Float16)(u1.x * inv); o[5] = (_Float16)(u1.y * inv);
        o[6] = (_Float16)(u1.z * inv); o[7] = (_Float16)(u1.w * inv);
        ((f16x8*)Bp)[((c * 4 + kq) * 16 + nt) * 64 + lane] = o;
    } else {
        const int r = blk - 128;                 // 0..255 = b*8+c
        const float* xp = x + (size_t)r * L_;
        for (int i = tid; i < L_ / 4; i += 256)
            ((float4*)xr)[i] = ((const float4*)xp)[i];
        __syncthreads();

        float* ivp = invn + (size_t)r * L_;
        const int w0 = tid * 8;
        float ss = 0.f;
        if (w0 < W_) {
            #pragma unroll
            for (int j = 0; j < S_; ++j) { float v = xr[w0 + j]; ss += v * v; }
        }
        #pragma unroll
        for (int u = 0; u < 8; ++u) {
            int w = w0 + u;
            float o = 0.f;
            if (u > 0 && w < W_)
                ss += xr[w + 63] * xr[w + 63] - xr[w - 1] * xr[w - 1];
            if (w < W_) o = 0.125f / fmaxf(sqrtf(ss), 1e-8f);
            if (w < L_) ivp[w] = o;
        }

        _Float16* p0 = xh0 + (size_t)r * XS_;
        _Float16* p1 = xh1 + (size_t)r * XS_;
        for (int i = tid; i < XS_ / 8; i += 256) {
            f16x8 o0, o1;
            #pragma unroll
            for (int j = 0; j < 8; ++j) {
                int e = i * 8 + j;
                o0[j] = (_Float16)((e     < L_) ? xr[e]     : 0.f);
                o1[j] = (_Float16)((e + 1 < L_) ? xr[e + 1] : 0.f);
            }
            ((f16x8*)p0)[i] = o0;
            ((f16x8*)p1)[i] = o1;
        }
        if (r < 64) out[r * 256 + tid] = 0.f;    // zero output
    }
}

// global -> LDS direct copy, 16B per (active) lane
__device__ __forceinline__ void glds16(const void* g, void* l) {
    __builtin_amdgcn_global_load_lds(
        (const __attribute__((address_space(1))) unsigned int*)g,
        (__attribute__((address_space(3))) unsigned int*)l, 16, 0, 0);
}

union AFrag { unsigned int u[4]; f16x8 v; };

// ---- main: all operands from LDS; barrier-free c-loop ----
// grid (8 wt, 8 ng, 32 b) = 2048 blocks, 4 waves. Wave: 64 windows (2x32)
// x 64 q (2x32), acc = 4 x f32x16 = 64. Staged once: 64KB B-panel + 13KB
// x-slab (2 parity copies x 8 c x 416 f16). Per c per wave: 24 LDS dword
// reads (6 Hankel A-frags) + 8 ds_read_b128 (B) + 2 iv loads + 16 MFMA.
__global__ __launch_bounds__(256, 2)
void mcs_k(const _Float16* __restrict__ xh0, const _Float16* __restrict__ xh1,
           const _Float16* __restrict__ Bp, const float* __restrict__ invn,
           float* __restrict__ out) {
    const int wt  = blockIdx.x;           // 0..7  256-window tile
    const int ng  = blockIdx.y;           // 0..7  64-q panel
    const int b   = blockIdx.z;
    const int tid = threadIdx.x;
    const int lane = tid & 63;
    const int wv   = tid >> 6;            // window subgroup 0..3

    const int l31 = lane & 31;
    const int lh  = lane >> 5;
    const int WBLK = wt * 256;            // block window base
    const int Wb   = WBLK + wv * 64;      // wave window base
    const int m0   = Wb + l31;
    const int m1   = Wb + 32 + l31;

    __shared__ __attribute__((aligned(16))) f16x8   Bs[64][64];      // 64 KB
    __shared__ __attribute__((aligned(16))) _Float16 xs[16 * XSLAB_]; // 13 KB

    // ---- stage B-panel (as v8): wave wv stages units e = wv*16..+15 ----
    {
        const f16x8* bp = (const f16x8*)Bp;
        #pragma unroll
        for (int u = 0; u < 16; ++u) {
            const int e   = wv * 16 + u;
            const int c   = e >> 3;
            const int sub = e & 7;                    // ks*2 + nt
            const int src = ((c * 4 + (sub >> 1)) * 16 + ng * 2 + (sub & 1)) * 64;
            glds16(bp + src + lane, &Bs[e][0]);
        }
    }
    // ---- stage x-slab: region r = c*2+par holds xh{par}[row, WBLK..+415] ----
    if (lane < 52) {                       // 52 lanes x 16B = 832B = 416 f16
        #pragma unroll
        for (int u = 0; u < 4; ++u) {
            const int r   = wv * 4 + u;
            const int c   = r >> 1;
            const int par = r & 1;
            const _Float16* srcp = (par ? xh1 : xh0)
                + (size_t)(b * C_ + c) * XS_ + WBLK + lane * 8;
            glds16(srcp, &xs[r * XSLAB_]);
        }
    }

    const float* ivbase = invn + (size_t)b * C_ * L_;

    f32x16 acc[2][2];
    #pragma unroll
    for (int mt = 0; mt < 2; ++mt)
        #pragma unroll
        for (int nt = 0; nt < 2; ++nt)
            #pragma unroll
            for (int r = 0; r < 16; ++r) acc[mt][nt][r] = 0.f;

    // per-lane dword index into xs for c=0:
    // g(p) dwords = base + p*8 + {0..3}; odd lanes read the shifted copy
    const int par = l31 & 1;
    const unsigned int* xsl = (const unsigned int*)xs;
    const int xdw0 = par * XSLDW_ + ((wv * 64 + l31 - par) >> 1) + lh * 4;

    __syncthreads();                      // B-panel + x-slab ready

    #pragma unroll 2
    for (int c = 0; c < C_; ++c) {
        // A: 6 Hankel frags g(0..5); a(mt,ks) = g(2mt+ks)
        AFrag g[6];
        const int cb = c * (2 * XSLDW_) + xdw0;
        #pragma unroll
        for (int p = 0; p < 6; ++p)
            #pragma unroll
            for (int t = 0; t < 4; ++t)
                g[p].u[t] = xsl[cb + p * 8 + t];

        const float iv0 = ivbase[(size_t)c * L_ + m0];   // 0 for invalid w
        const float iv1 = ivbase[(size_t)c * L_ + m1];
        const _Float16 h0 = (_Float16)iv0, h1 = (_Float16)iv1;
        f16x8 is0, is1;
        #pragma unroll
        for (int j = 0; j < 8; ++j) { is0[j] = h0; is1[j] = h1; }

        // B: 8 lane-contiguous ds_read_b128 from the persistent panel
        f16x8 bf[8];
        #pragma unroll
        for (int ks = 0; ks < 4; ++ks)
            #pragma unroll
            for (int nt = 0; nt < 2; ++nt)
                bf[ks * 2 + nt] = Bs[c * 8 + ks * 2 + nt][lane];

        __builtin_amdgcn_s_setprio(1);
        #pragma unroll
        for (int ks = 0; ks < 4; ++ks) {
            f16x8 a0 = g[ks].v     * is0;       // v_pk_mul_f16 x4
            f16x8 a1 = g[ks + 2].v * is1;
            #pragma unroll
            for (int nt = 0; nt < 2; ++nt) {
                acc[0][nt] = __builtin_amdgcn_mfma_f32_32x32x16_f16(
                    a0, bf[ks * 2 + nt], acc[0][nt], 0, 0, 0);
                acc[1][nt] = __builtin_amdgcn_mfma_f32_32x32x16_f16(
                    a1, bf[ks * 2 + nt], acc[1][nt], 0, 0, 0);
            }
        }
        __builtin_amdgcn_s_setprio(0);
    }

    // epilogue: relu + max over windows; col(q) = lane&31; fold lane^32;
    // waves cover disjoint windows -> atomicMax combines (values >= 0).
    #pragma unroll
    for (int nt = 0; nt < 2; ++nt) {
        float v = 0.f;
        #pragma unroll
        for (int mt = 0; mt < 2; ++mt)
            #pragma unroll
            for (int r = 0; r < 16; ++r) v = fmaxf(v, acc[mt][nt][r]);
        v = fmaxf(v, __shfl_xor(v, 32));
        if (lane < 32)
            atomicMax((unsigned int*)(out + (size_t)b * K_ + ng * 64 + nt * 32 + l31),
                      __float_as_uint(v));
    }
}

extern "C" void kernel_launch(void* const* d_in, const int* in_sizes, int n_in,
                              void* d_out, int out_size, void* d_ws, size_t ws_size,
                              hipStream_t stream) {
    const float* x  = (const float*)d_in[0];   // (32, 8, 2048) fp32
    const float* sh = (const float*)d_in[1];   // (8, 512, 64) fp32
    float* out = (float*)d_out;                // (32, 1, 512) fp32

    // workspace: Bp 512KB | xh0 | xh1 | invn (invn LAST so the x-slab
    // staging's 62B tail overrun on the final xh1 row lands in valid memory)
    _Float16* Bp   = (_Float16*)d_ws;
    _Float16* xh0  = (_Float16*)((char*)d_ws + (512 << 10));
    _Float16* xh1  = xh0 + (size_t)B_ * C_ * XS_;
    float*    invn = (float*)(xh1 + (size_t)B_ * C_ * XS_);

    prep_k<<<dim3(384), dim3(256), 0, stream>>>(x, sh, Bp, invn, xh0, xh1, out);
    mcs_k<<<dim3(8, 8, B_), dim3(256), 0, stream>>>(xh0, xh1, Bp, invn, out);
}